// Round 2
// baseline (214.198 us; speedup 1.0000x reference)
//
#include <hip/hip_runtime.h>
#include <hip/hip_bf16.h>

typedef __attribute__((ext_vector_type(8))) short short8;
typedef __attribute__((ext_vector_type(4))) float floatx4;
typedef unsigned short ushort_t;
typedef unsigned int uint_t;

#define DOUT   256
#define KPAD   864          // 320 + 320 + 224 (segments padded to x32)
#define XPITCH 872          // +8 elements => row stride 1744 B (16B-aligned, odd multiple)
#define TB     32           // tokens per block
#define NTOK   16384        // 32*512

// fp32 -> bf16 (round-nearest-even), bit result
static __device__ inline ushort_t f2bf(float f) {
    union { float f; uint_t u; } a; a.f = f;
    uint_t u = a.u;
    return (ushort_t)((u + 0x7FFFu + ((u >> 16) & 1u)) >> 16);
}
static __device__ inline uint_t pack2bf(float x, float y) {
    return (uint_t)f2bf(x) | ((uint_t)f2bf(y) << 16);
}

// ---------------------------------------------------------------------------
// Prep 1: u[k] = W_cat[k,:] . Wa   (padded K layout, zeros in pads)
//         lb[n] = b_n . Wa + ba          (all fp32)
// ---------------------------------------------------------------------------
__global__ __launch_bounds__(64) void k_prep_u(
    const float* __restrict__ W0, const float* __restrict__ W1,
    const float* __restrict__ W2,
    const float* __restrict__ b0, const float* __restrict__ b1,
    const float* __restrict__ b2,
    const float* __restrict__ Wa, const float* __restrict__ ba,
    float* __restrict__ u, float* __restrict__ lb)
{
    int kp = blockIdx.x;
    int lane = threadIdx.x;
    const float* row = nullptr;
    if (kp < 320)       { if (kp < 300) row = W0 + kp * DOUT; }
    else if (kp < 640)  { int o = kp - 320; if (o < 300) row = W1 + o * DOUT; }
    else if (kp < 864)  { int o = kp - 640; if (o < 200) row = W2 + o * DOUT; }
    else                { int n = kp - 864; row = (n == 0) ? b0 : ((n == 1) ? b1 : b2); }
    float acc = 0.f;
    if (row) {
        for (int j = lane; j < DOUT; j += 64)
            acc += row[j] * Wa[j];
    }
    for (int off = 32; off > 0; off >>= 1) acc += __shfl_down(acc, off);
    if (lane == 0) {
        if (kp < 864) u[kp] = acc;
        else          lb[kp - 864] = acc + ba[0];
    }
}

// ---------------------------------------------------------------------------
// Prep 2: Wt[n][k] = bf16(W_cat[k][n])  (padded K layout, zeros in pads)
// ---------------------------------------------------------------------------
__global__ __launch_bounds__(256) void k_prep_t(
    const float* __restrict__ W0, const float* __restrict__ W1,
    const float* __restrict__ W2, ushort_t* __restrict__ Wt)
{
    __shared__ ushort_t tile[32][256];
    int tid = threadIdx.x;
    int k0 = blockIdx.x * 32;
    for (int idx = tid; idx < 32 * 256; idx += 256) {
        int kk = idx >> 8, d = idx & 255;
        int kp = k0 + kk;
        float v = 0.f;
        const float* src = nullptr;
        if (kp < 320)      { if (kp < 300) src = W0 + kp * DOUT; }
        else if (kp < 640) { int o = kp - 320; if (o < 300) src = W1 + o * DOUT; }
        else               { int o = kp - 640; if (o < 200) src = W2 + o * DOUT; }
        if (src) v = src[d];
        tile[kk][d] = f2bf(v);
    }
    __syncthreads();
    int d = tid;
    #pragma unroll
    for (int g = 0; g < 4; ++g) {
        union { uint4 v; ushort_t s[8]; } p;
        #pragma unroll
        for (int j = 0; j < 8; ++j) p.s[j] = tile[g * 8 + j][d];
        *(uint4*)(Wt + (size_t)d * KPAD + k0 + g * 8) = p.v;
    }
}

// ---------------------------------------------------------------------------
// Main: gather(fp32->bf16) -> logits/softmax -> 3-segment MFMA GEMM -> epilogue
// Block: 256 threads (4 waves), 32 tokens; grid 512.
// ---------------------------------------------------------------------------
#define MFMA_STEP(ACC, KC) {                                                   \
    short8 a0 = *(const short8*)&Xs[mrow][(KC) + kg8];                         \
    short8 a1 = *(const short8*)&Xs[16 + mrow][(KC) + kg8];                    \
    short8 bv0 = *(const short8*)(bp0 + (KC));                                 \
    short8 bv1 = *(const short8*)(bp1 + (KC));                                 \
    short8 bv2 = *(const short8*)(bp2 + (KC));                                 \
    short8 bv3 = *(const short8*)(bp3 + (KC));                                 \
    ACC[0][0] = __builtin_amdgcn_mfma_f32_16x16x32_bf16(a0, bv0, ACC[0][0], 0, 0, 0); \
    ACC[1][0] = __builtin_amdgcn_mfma_f32_16x16x32_bf16(a1, bv0, ACC[1][0], 0, 0, 0); \
    ACC[0][1] = __builtin_amdgcn_mfma_f32_16x16x32_bf16(a0, bv1, ACC[0][1], 0, 0, 0); \
    ACC[1][1] = __builtin_amdgcn_mfma_f32_16x16x32_bf16(a1, bv1, ACC[1][1], 0, 0, 0); \
    ACC[0][2] = __builtin_amdgcn_mfma_f32_16x16x32_bf16(a0, bv2, ACC[0][2], 0, 0, 0); \
    ACC[1][2] = __builtin_amdgcn_mfma_f32_16x16x32_bf16(a1, bv2, ACC[1][2], 0, 0, 0); \
    ACC[0][3] = __builtin_amdgcn_mfma_f32_16x16x32_bf16(a0, bv3, ACC[0][3], 0, 0, 0); \
    ACC[1][3] = __builtin_amdgcn_mfma_f32_16x16x32_bf16(a1, bv3, ACC[1][3], 0, 0, 0); \
}

__global__ __launch_bounds__(256, 2) void k_main(
    const int* __restrict__ ids,
    const float* __restrict__ E0, const float* __restrict__ E1,
    const float* __restrict__ E2,
    const float* __restrict__ b0, const float* __restrict__ b1,
    const float* __restrict__ b2,
    const float* __restrict__ u, const float* __restrict__ lb,
    const ushort_t* __restrict__ Wt,
    float* __restrict__ out)
{
    __shared__ __align__(16) ushort_t Xs[TB][XPITCH];   // 55808 B (bf16 tokens)
    __shared__ float uS[KPAD];                          // 3456 B
    __shared__ float alphaS[TB][4];                     // 512 B

    int tid = threadIdx.x;
    int tok0 = blockIdx.x * TB;

    // stage u
    for (int i = tid; i < KPAD; i += 256) uS[i] = u[i];

    // gather: 8 threads per token row; fp32 float2 loads -> packed bf16 dwords
    int trow = tid >> 3, sub = tid & 7;
    int id = ids[tok0 + trow];
    uint_t* Xd = (uint_t*)&Xs[trow][0];
    const float2* E0v = (const float2*)E0;   // 150 float2 per row
    const float2* E1v = (const float2*)E1;   // 150 float2 per row
    const float2* E2v = (const float2*)E2;   // 100 float2 per row
    for (int i = sub; i < 150; i += 8) { float2 t = E0v[(size_t)id * 150 + i]; Xd[i]       = pack2bf(t.x, t.y); }
    for (int i = sub; i < 150; i += 8) { float2 t = E1v[(size_t)id * 150 + i]; Xd[160 + i] = pack2bf(t.x, t.y); }
    for (int i = sub; i < 100; i += 8) { float2 t = E2v[(size_t)id * 100 + i]; Xd[320 + i] = pack2bf(t.x, t.y); }
    for (int i = 150 + sub; i < 160; i += 8) Xd[i] = 0u;   // seg0 pad
    for (int i = 310 + sub; i < 320; i += 8) Xd[i] = 0u;   // seg1 pad
    for (int i = 420 + sub; i < 436; i += 8) Xd[i] = 0u;   // seg2 + row pad
    __syncthreads();

    // logits: l_n = x_seg_n . u_seg_n  (pads are zero)
    const ushort_t* xr = Xs[trow];
    float l0 = 0.f, l1 = 0.f, l2 = 0.f;
    for (int k = sub * 2; k < 320; k += 16) {
        uint_t p = *(const uint_t*)&xr[k];
        float2 uu = *(const float2*)&uS[k];
        l0 += __uint_as_float(p << 16) * uu.x + __uint_as_float(p & 0xFFFF0000u) * uu.y;
    }
    for (int k = 320 + sub * 2; k < 640; k += 16) {
        uint_t p = *(const uint_t*)&xr[k];
        float2 uu = *(const float2*)&uS[k];
        l1 += __uint_as_float(p << 16) * uu.x + __uint_as_float(p & 0xFFFF0000u) * uu.y;
    }
    for (int k = 640 + sub * 2; k < 864; k += 16) {
        uint_t p = *(const uint_t*)&xr[k];
        float2 uu = *(const float2*)&uS[k];
        l2 += __uint_as_float(p << 16) * uu.x + __uint_as_float(p & 0xFFFF0000u) * uu.y;
    }
    for (int off = 4; off > 0; off >>= 1) {
        l0 += __shfl_down(l0, off);
        l1 += __shfl_down(l1, off);
        l2 += __shfl_down(l2, off);
    }
    if (sub == 0) {
        l0 += lb[0]; l1 += lb[1]; l2 += lb[2];
        float m = fmaxf(l0, fmaxf(l1, l2));
        float e0 = __expf(l0 - m), e1 = __expf(l1 - m), e2 = __expf(l2 - m);
        float inv = 1.f / (e0 + e1 + e2);
        alphaS[trow][0] = e0 * inv;
        alphaS[trow][1] = e1 * inv;
        alphaS[trow][2] = e2 * inv;
    }
    __syncthreads();

    // MFMA GEMM: 3 segment accumulators (p0, p1, p2 tiles)
    int lane = tid & 63;
    int w = tid >> 6;               // wave id: n-range [64w, 64w+64)
    int mrow = lane & 15;
    int kg8 = (lane >> 4) * 8;

    const ushort_t* bp0 = Wt + (size_t)(w * 64 +  0 + mrow) * KPAD + kg8;
    const ushort_t* bp1 = Wt + (size_t)(w * 64 + 16 + mrow) * KPAD + kg8;
    const ushort_t* bp2 = Wt + (size_t)(w * 64 + 32 + mrow) * KPAD + kg8;
    const ushort_t* bp3 = Wt + (size_t)(w * 64 + 48 + mrow) * KPAD + kg8;

    floatx4 acc0[2][4], acc1[2][4], acc2[2][4];
    #pragma unroll
    for (int mt = 0; mt < 2; ++mt)
        #pragma unroll
        for (int nt = 0; nt < 4; ++nt) {
            floatx4 z = {0.f, 0.f, 0.f, 0.f};
            acc0[mt][nt] = z; acc1[mt][nt] = z; acc2[mt][nt] = z;
        }

    #pragma unroll
    for (int kc = 0; kc < 320; kc += 32)   MFMA_STEP(acc0, kc);
    #pragma unroll
    for (int kc = 320; kc < 640; kc += 32) MFMA_STEP(acc1, kc);
    #pragma unroll
    for (int kc = 640; kc < 864; kc += 32) MFMA_STEP(acc2, kc);

    // epilogue: out = a0*(p0+b0) + a1*(p1+b1) + a2*(p2+b2)   (fp32 out)
    float bb0[4], bb1[4], bb2[4];
    #pragma unroll
    for (int nt = 0; nt < 4; ++nt) {
        int n = w * 64 + nt * 16 + mrow;
        bb0[nt] = b0[n];
        bb1[nt] = b1[n];
        bb2[nt] = b2[n];
    }
    #pragma unroll
    for (int mt = 0; mt < 2; ++mt) {
        #pragma unroll
        for (int r = 0; r < 4; ++r) {
            int tok = mt * 16 + (lane >> 4) * 4 + r;
            float a0 = alphaS[tok][0], a1 = alphaS[tok][1], a2 = alphaS[tok][2];
            size_t rowoff = (size_t)(tok0 + tok) * DOUT;
            #pragma unroll
            for (int nt = 0; nt < 4; ++nt) {
                int n = w * 64 + nt * 16 + mrow;
                float v = a0 * (acc0[mt][nt][r] + bb0[nt])
                        + a1 * (acc1[mt][nt][r] + bb1[nt])
                        + a2 * (acc2[mt][nt][r] + bb2[nt]);
                out[rowoff + n] = v;
            }
        }
    }
}

extern "C" void kernel_launch(void* const* d_in, const int* in_sizes, int n_in,
                              void* d_out, int out_size, void* d_ws, size_t ws_size,
                              hipStream_t stream) {
    const int*   ids = (const int*)d_in[0];
    const float* E0  = (const float*)d_in[1];
    const float* E1  = (const float*)d_in[2];
    const float* E2  = (const float*)d_in[3];
    const float* W0  = (const float*)d_in[4];
    const float* b0  = (const float*)d_in[5];
    const float* W1  = (const float*)d_in[6];
    const float* b1  = (const float*)d_in[7];
    const float* W2  = (const float*)d_in[8];
    const float* b2  = (const float*)d_in[9];
    const float* Wa  = (const float*)d_in[10];
    const float* ba  = (const float*)d_in[11];

    float* u     = (float*)d_ws;                       // 864 floats
    float* lb    = u + KPAD;                           // 3 floats
    ushort_t* Wt = (ushort_t*)((char*)d_ws + 4096);    // 256*864 bf16 = 432 KB

    k_prep_u<<<KPAD + 3, 64, 0, stream>>>(W0, W1, W2, b0, b1, b2, Wa, ba, u, lb);
    k_prep_t<<<KPAD / 32, 256, 0, stream>>>(W0, W1, W2, Wt);
    k_main<<<NTOK / TB, 256, 0, stream>>>(ids, E0, E1, E2, b0, b1, b2, u, lb, Wt,
                                          (float*)d_out);
}

// Round 3
// 205.189 us; speedup vs baseline: 1.0439x; 1.0439x over previous
//
#include <hip/hip_runtime.h>
#include <hip/hip_bf16.h>

typedef __attribute__((ext_vector_type(8))) short short8;
typedef __attribute__((ext_vector_type(4))) float floatx4;
typedef unsigned short ushort_t;
typedef unsigned int uint_t;

#define DOUT   256
#define KPAD   864          // 320 + 320 + 224 (segments padded to x32)
#define XPITCH 872          // row stride 1744 B (16B-aligned, 20-bank offset between rows)
#define TB     32           // tokens per block
#define NTOK   16384        // 32*512
#define NPREP_T 27          // transpose blocks (864/32)
#define NPREP_U 217         // 217*4 >= 867 kp rows

// fp32 -> bf16 (round-nearest-even)
static __device__ inline ushort_t f2bf(float f) {
    union { float f; uint_t u; } a; a.f = f;
    uint_t u = a.u;
    return (ushort_t)((u + 0x7FFFu + ((u >> 16) & 1u)) >> 16);
}
static __device__ inline uint_t pack2bf(float x, float y) {
    return (uint_t)f2bf(x) | ((uint_t)f2bf(y) << 16);
}

// ---------------------------------------------------------------------------
// Merged prep:
//  blocks [0, 27):     Wt[n][k] = bf16(W_cat[k][n])  (padded K, zeros in pads)
//  blocks [27, 27+217): u[k] = W_cat[k,:] . Wa ; lb[n] = b_n . Wa + ba
// ---------------------------------------------------------------------------
__global__ __launch_bounds__(256) void k_prep(
    const float* __restrict__ W0, const float* __restrict__ W1,
    const float* __restrict__ W2,
    const float* __restrict__ b0, const float* __restrict__ b1,
    const float* __restrict__ b2,
    const float* __restrict__ Wa, const float* __restrict__ ba,
    float* __restrict__ u, float* __restrict__ lb, ushort_t* __restrict__ Wt)
{
    __shared__ ushort_t tile[32][256];
    int tid = threadIdx.x;
    if (blockIdx.x < NPREP_T) {
        int k0 = blockIdx.x * 32;
        for (int idx = tid; idx < 32 * 256; idx += 256) {
            int kk = idx >> 8, d = idx & 255;
            int kp = k0 + kk;
            float v = 0.f;
            const float* src = nullptr;
            if (kp < 320)      { if (kp < 300) src = W0 + kp * DOUT; }
            else if (kp < 640) { int o = kp - 320; if (o < 300) src = W1 + o * DOUT; }
            else               { int o = kp - 640; if (o < 200) src = W2 + o * DOUT; }
            if (src) v = src[d];
            tile[kk][d] = f2bf(v);
        }
        __syncthreads();
        int d = tid;
        #pragma unroll
        for (int g = 0; g < 4; ++g) {
            union { uint4 v; ushort_t s[8]; } p;
            #pragma unroll
            for (int j = 0; j < 8; ++j) p.s[j] = tile[g * 8 + j][d];
            *(uint4*)(Wt + (size_t)d * KPAD + k0 + g * 8) = p.v;
        }
    } else {
        int lane = tid & 63;
        int w = tid >> 6;
        int kp = (blockIdx.x - NPREP_T) * 4 + w;
        if (kp > 866) return;
        const float* row = nullptr;
        if (kp < 320)       { if (kp < 300) row = W0 + kp * DOUT; }
        else if (kp < 640)  { int o = kp - 320; if (o < 300) row = W1 + o * DOUT; }
        else if (kp < 864)  { int o = kp - 640; if (o < 200) row = W2 + o * DOUT; }
        else                { int n = kp - 864; row = (n == 0) ? b0 : ((n == 1) ? b1 : b2); }
        float acc = 0.f;
        if (row) {
            #pragma unroll
            for (int j = lane; j < DOUT; j += 64)
                acc += row[j] * Wa[j];
        }
        for (int off = 32; off > 0; off >>= 1) acc += __shfl_down(acc, off);
        if (lane == 0) {
            if (kp < 864) u[kp] = acc;
            else          lb[kp - 864] = acc + ba[0];
        }
    }
}

// ---------------------------------------------------------------------------
// Main: gather(float4, fp32->bf16) + fused fp32 logits -> softmax -> MFMA GEMM
// Block: 512 threads (8 waves), 32 tokens; grid 512; 2 blocks/CU, 16 waves/CU.
// ---------------------------------------------------------------------------
#define MFMA_STEP(ACC, KC) {                                                   \
    short8 a0 = *(const short8*)&Xs[mrow][(KC) + kg8];                         \
    short8 a1 = *(const short8*)&Xs[16 + mrow][(KC) + kg8];                    \
    short8 bv0 = *(const short8*)(bp0 + (KC));                                 \
    short8 bv1 = *(const short8*)(bp1 + (KC));                                 \
    ACC[0][0] = __builtin_amdgcn_mfma_f32_16x16x32_bf16(a0, bv0, ACC[0][0], 0, 0, 0); \
    ACC[1][0] = __builtin_amdgcn_mfma_f32_16x16x32_bf16(a1, bv0, ACC[1][0], 0, 0, 0); \
    ACC[0][1] = __builtin_amdgcn_mfma_f32_16x16x32_bf16(a0, bv1, ACC[0][1], 0, 0, 0); \
    ACC[1][1] = __builtin_amdgcn_mfma_f32_16x16x32_bf16(a1, bv1, ACC[1][1], 0, 0, 0); \
}

__global__ __launch_bounds__(512, 4) void k_main(
    const int* __restrict__ ids,
    const float* __restrict__ E0, const float* __restrict__ E1,
    const float* __restrict__ E2,
    const float* __restrict__ b0, const float* __restrict__ b1,
    const float* __restrict__ b2,
    const float* __restrict__ u, const float* __restrict__ lb,
    const ushort_t* __restrict__ Wt,
    float* __restrict__ out)
{
    __shared__ __align__(16) ushort_t Xs[TB][XPITCH];   // 55808 B (bf16 tokens)
    __shared__ float alphaS[TB][4];                     // 512 B

    int tid = threadIdx.x;
    int tok0 = blockIdx.x * TB;

    // gather: 16 threads per token row; float4 loads; fused fp32 logit partials
    int trow = tid >> 4, sub = tid & 15;
    int id = ids[tok0 + trow];
    uint2* Xd2 = (uint2*)&Xs[trow][0];                  // 218 uint2 per row
    const float4* E0v = (const float4*)E0;              // 75 per row
    const float4* E1v = (const float4*)E1;              // 75 per row
    const float4* E2v = (const float4*)E2;              // 50 per row
    float l0 = 0.f, l1 = 0.f, l2 = 0.f;

    #pragma unroll
    for (int i = sub; i < 75; i += 16) {
        float4 t = E0v[(size_t)id * 75 + i];
        float4 uu = *(const float4*)(u + 4 * i);
        l0 += t.x * uu.x + t.y * uu.y + t.z * uu.z + t.w * uu.w;
        Xd2[i] = make_uint2(pack2bf(t.x, t.y), pack2bf(t.z, t.w));
    }
    #pragma unroll
    for (int i = sub; i < 75; i += 16) {
        float4 t = E1v[(size_t)id * 75 + i];
        float4 uu = *(const float4*)(u + 320 + 4 * i);
        l1 += t.x * uu.x + t.y * uu.y + t.z * uu.z + t.w * uu.w;
        Xd2[80 + i] = make_uint2(pack2bf(t.x, t.y), pack2bf(t.z, t.w));
    }
    #pragma unroll
    for (int i = sub; i < 50; i += 16) {
        float4 t = E2v[(size_t)id * 50 + i];
        float4 uu = *(const float4*)(u + 640 + 4 * i);
        l2 += t.x * uu.x + t.y * uu.y + t.z * uu.z + t.w * uu.w;
        Xd2[160 + i] = make_uint2(pack2bf(t.x, t.y), pack2bf(t.z, t.w));
    }
    uint2 z2 = make_uint2(0u, 0u);
    for (int i = 75 + sub;  i < 80;  i += 16) Xd2[i] = z2;   // seg0 pad
    for (int i = 155 + sub; i < 160; i += 16) Xd2[i] = z2;   // seg1 pad
    for (int i = 210 + sub; i < 218; i += 16) Xd2[i] = z2;   // seg2 + row pad

    // 16-lane tree reduce (token's lanes are contiguous within a wave)
    #pragma unroll
    for (int off = 8; off > 0; off >>= 1) {
        l0 += __shfl_down(l0, off);
        l1 += __shfl_down(l1, off);
        l2 += __shfl_down(l2, off);
    }
    if (sub == 0) {
        l0 += lb[0]; l1 += lb[1]; l2 += lb[2];
        float m = fmaxf(l0, fmaxf(l1, l2));
        float e0 = __expf(l0 - m), e1 = __expf(l1 - m), e2 = __expf(l2 - m);
        float inv = 1.f / (e0 + e1 + e2);
        alphaS[trow][0] = e0 * inv;
        alphaS[trow][1] = e1 * inv;
        alphaS[trow][2] = e2 * inv;
    }
    __syncthreads();

    // MFMA GEMM: wave w owns n in [32w, 32w+32); 3 segment accumulator sets
    int lane = tid & 63;
    int w = tid >> 6;               // 0..7
    int mrow = lane & 15;
    int kg8 = (lane >> 4) * 8;

    const ushort_t* bp0 = Wt + (size_t)(w * 32 +  0 + mrow) * KPAD + kg8;
    const ushort_t* bp1 = Wt + (size_t)(w * 32 + 16 + mrow) * KPAD + kg8;

    floatx4 acc0[2][2], acc1[2][2], acc2[2][2];
    #pragma unroll
    for (int mt = 0; mt < 2; ++mt)
        #pragma unroll
        for (int nt = 0; nt < 2; ++nt) {
            floatx4 z = {0.f, 0.f, 0.f, 0.f};
            acc0[mt][nt] = z; acc1[mt][nt] = z; acc2[mt][nt] = z;
        }

    #pragma unroll
    for (int kc = 0; kc < 320; kc += 32)   MFMA_STEP(acc0, kc);
    #pragma unroll
    for (int kc = 320; kc < 640; kc += 32) MFMA_STEP(acc1, kc);
    #pragma unroll
    for (int kc = 640; kc < 864; kc += 32) MFMA_STEP(acc2, kc);

    // epilogue: out = a0*(p0+b0) + a1*(p1+b1) + a2*(p2+b2)   (fp32 out)
    float bb0[2], bb1[2], bb2[2];
    #pragma unroll
    for (int nt = 0; nt < 2; ++nt) {
        int n = w * 32 + nt * 16 + mrow;
        bb0[nt] = b0[n];
        bb1[nt] = b1[n];
        bb2[nt] = b2[n];
    }
    #pragma unroll
    for (int mt = 0; mt < 2; ++mt) {
        #pragma unroll
        for (int r = 0; r < 4; ++r) {
            int tok = mt * 16 + (lane >> 4) * 4 + r;
            float a0 = alphaS[tok][0], a1 = alphaS[tok][1], a2 = alphaS[tok][2];
            size_t rowoff = (size_t)(tok0 + tok) * DOUT;
            #pragma unroll
            for (int nt = 0; nt < 2; ++nt) {
                int n = w * 32 + nt * 16 + mrow;
                float v = a0 * (acc0[mt][nt][r] + bb0[nt])
                        + a1 * (acc1[mt][nt][r] + bb1[nt])
                        + a2 * (acc2[mt][nt][r] + bb2[nt]);
                out[rowoff + n] = v;
            }
        }
    }
}

extern "C" void kernel_launch(void* const* d_in, const int* in_sizes, int n_in,
                              void* d_out, int out_size, void* d_ws, size_t ws_size,
                              hipStream_t stream) {
    const int*   ids = (const int*)d_in[0];
    const float* E0  = (const float*)d_in[1];
    const float* E1  = (const float*)d_in[2];
    const float* E2  = (const float*)d_in[3];
    const float* W0  = (const float*)d_in[4];
    const float* b0  = (const float*)d_in[5];
    const float* W1  = (const float*)d_in[6];
    const float* b1  = (const float*)d_in[7];
    const float* W2  = (const float*)d_in[8];
    const float* b2  = (const float*)d_in[9];
    const float* Wa  = (const float*)d_in[10];
    const float* ba  = (const float*)d_in[11];

    float* u     = (float*)d_ws;                       // 864 floats
    float* lb    = u + KPAD;                           // 3 floats
    ushort_t* Wt = (ushort_t*)((char*)d_ws + 4096);    // 256*864 bf16 = 432 KB

    k_prep<<<NPREP_T + NPREP_U, 256, 0, stream>>>(W0, W1, W2, b0, b1, b2, Wa, ba,
                                                  u, lb, Wt);
    k_main<<<NTOK / TB, 512, 0, stream>>>(ids, E0, E1, E2, b0, b1, b2, u, lb, Wt,
                                          (float*)d_out);
}